// Round 1
// baseline (22321.066 us; speedup 1.0000x reference)
//
#include <hip/hip_runtime.h>
#include <math.h>

#define N_NODES 100000
#define N_EDGES 3200000
#define NFEAT 512
#define NHID 256
#define NCLASS 16
#define NLAYERS 8

#define SCAN_CHUNK 1024
#define NB ((N_NODES + SCAN_CHUNK - 1) / SCAN_CHUNK)   // 98

// ---------------- CSR build ----------------
__global__ void k_hist(const int* __restrict__ dst, int* __restrict__ cnt) {
  int i = blockIdx.x * 256 + threadIdx.x;
  if (i < N_EDGES) atomicAdd(&cnt[dst[i]], 1);
}

__global__ void k_blocksum(const int* __restrict__ cnt, int* __restrict__ bs) {
  __shared__ int red[256];
  int b = blockIdx.x, t = threadIdx.x;
  int s = 0;
  int base = b * SCAN_CHUNK;
  for (int j = 0; j < 4; ++j) {
    int i = base + t + j * 256;
    if (i < N_NODES) s += cnt[i];
  }
  red[t] = s;
  __syncthreads();
  for (int off = 128; off > 0; off >>= 1) {
    if (t < off) red[t] += red[t + off];
    __syncthreads();
  }
  if (t == 0) bs[b] = red[0];
}

__global__ void k_scan_top(int* __restrict__ bs, int* __restrict__ rp) {
  if (threadIdx.x == 0) {
    int run = 0;
    for (int b = 0; b < NB; ++b) { int v = bs[b]; bs[b] = run; run += v; }
    rp[N_NODES] = run;
  }
}

__global__ void k_scan_write(const int* __restrict__ cnt, const int* __restrict__ bs,
                             int* __restrict__ rp) {
  __shared__ int tot[256];
  int b = blockIdx.x, t = threadIdx.x;
  int base = b * SCAN_CHUNK + t * 4;
  int v0 = 0, v1 = 0, v2 = 0, v3 = 0;
  if (base + 0 < N_NODES) v0 = cnt[base + 0];
  if (base + 1 < N_NODES) v1 = cnt[base + 1];
  if (base + 2 < N_NODES) v2 = cnt[base + 2];
  if (base + 3 < N_NODES) v3 = cnt[base + 3];
  int tsum = v0 + v1 + v2 + v3;
  tot[t] = tsum;
  __syncthreads();
  for (int off = 1; off < 256; off <<= 1) {
    int v = 0;
    if (t >= off) v = tot[t - off];
    __syncthreads();
    if (t >= off) tot[t] += v;
    __syncthreads();
  }
  int excl = tot[t] - tsum + bs[b];
  if (base + 0 < N_NODES) rp[base + 0] = excl;
  if (base + 1 < N_NODES) rp[base + 1] = excl + v0;
  if (base + 2 < N_NODES) rp[base + 2] = excl + v0 + v1;
  if (base + 3 < N_NODES) rp[base + 3] = excl + v0 + v1 + v2;
}

__global__ void k_fill(const int* __restrict__ src, const int* __restrict__ dst,
                       const float* __restrict__ w, const int* __restrict__ rp,
                       int* __restrict__ fill, int* __restrict__ col,
                       float* __restrict__ val) {
  int i = blockIdx.x * 256 + threadIdx.x;
  if (i < N_EDGES) {
    int d = dst[i];
    int pos = rp[d] + atomicAdd(&fill[d], 1);
    col[pos] = src[i];
    val[pos] = w[i];
  }
}

// ---------------- SpMM + fused support, feature-split ----------------
// Feature half [f0, f0+128): per-pass streaming set (h/2 + h0/2 + sup/2 +
// col/val = 179 MB) fits the 256 MB L3 -> gathers hit L3 (measured
// 146 us/half = 11.2 TB/s effective). At the L3-gather roofline.
__global__ __launch_bounds__(256)
void k_spmm_half(const int* __restrict__ rp, const int* __restrict__ col,
                 const float* __restrict__ val, const float* __restrict__ h,
                 const float* __restrict__ h0, float* __restrict__ sup, int f0) {
  int wave = threadIdx.x >> 6;
  int lane = threadIdx.x & 63;
  int node = blockIdx.x * 4 + wave;
  if (node >= N_NODES) return;
  int e0 = rp[node], e1 = rp[node + 1];
  const float2* __restrict__ hv = (const float2*)h;  // row stride 128 float2
  int fo = (f0 >> 1) + lane;

  float2 a0 = make_float2(0.f, 0.f);
  float2 a1 = make_float2(0.f, 0.f);
  float2 a2 = make_float2(0.f, 0.f);
  float2 a3 = make_float2(0.f, 0.f);

  int e = e0;
  for (; e + 4 <= e1; e += 4) {
    int s0 = col[e], s1 = col[e + 1], s2 = col[e + 2], s3 = col[e + 3];
    float w0 = val[e], w1 = val[e + 1], w2 = val[e + 2], w3 = val[e + 3];
    float2 v0 = hv[(size_t)s0 * 128 + fo];
    float2 v1 = hv[(size_t)s1 * 128 + fo];
    float2 v2 = hv[(size_t)s2 * 128 + fo];
    float2 v3 = hv[(size_t)s3 * 128 + fo];
    a0.x += w0 * v0.x; a0.y += w0 * v0.y;
    a1.x += w1 * v1.x; a1.y += w1 * v1.y;
    a2.x += w2 * v2.x; a2.y += w2 * v2.y;
    a3.x += w3 * v3.x; a3.y += w3 * v3.y;
  }
  for (; e < e1; ++e) {
    int s0 = col[e];
    float w0 = val[e];
    float2 v0 = hv[(size_t)s0 * 128 + fo];
    a0.x += w0 * v0.x; a0.y += w0 * v0.y;
  }

  float2 acc;
  acc.x = (a0.x + a1.x) + (a2.x + a3.x);
  acc.y = (a0.y + a1.y) + (a2.y + a3.y);

  float2 z = ((const float2*)h0)[(size_t)node * 128 + fo];
  float2 o;
  o.x = 0.9f * acc.x + 0.1f * z.x;
  o.y = 0.9f * acc.y + 0.1f * z.y;
  ((float2*)sup)[(size_t)node * 128 + fo] = o;
}

// ---------------- GEMM, 128x256 tile (full N), BK=16, 8x16 micro-tile -------
// Rationale vs previous 128x128/8x8 version (35 TF, VALUBusy 58%):
//  * 8x16 micro: 6 ds_read_b128 per 128 FMAs (was 4 per 64) -> LDS-issue
//    demand drops from 1.5x to 1.125x of VALU cycles.
//  * Full-N tile: grid.y 2 -> 1, A staged once (halves A fetch traffic).
//  * Double-buffered LDS: B tile is a CONTIGUOUS 16KB slab of W ->
//    global_load_lds width=16 directly into the back buffer; A prefetched
//    global->reg before compute, transposed into back buffer after compute.
//    One __syncthreads per tile; its vmcnt drain is exactly the handoff.
//  * Bank layout: a-reads = 4 unique broadcast addrs/wave (banks 0-7/8-15/
//    16-23/24-31, conflict-free); b-reads at tx*4 + {0,64,128,192} = 2-way
//    alias = free; A-transpose writes 2-way = free.
// MODE 0: out1 = out2 = relu(A@W + bias)                  (A = x, K = 512)
// MODE 1: out1 = relu(theta*(A@W) + (1-theta)*A + hin)    (A = sup, K = 256)
__device__ __forceinline__ void async_copy16(void* lds_dst, const void* gsrc) {
  __builtin_amdgcn_global_load_lds(
      (const __attribute__((address_space(1))) unsigned int*)gsrc,
      (__attribute__((address_space(3))) unsigned int*)lds_dst, 16, 0, 0);
}

template <int MODE>
__global__ __launch_bounds__(256, 2)
void k_gemm(const float* __restrict__ A, const float* __restrict__ W, int K,
            const float* __restrict__ bias, const float* __restrict__ hin,
            float* __restrict__ out1, float* __restrict__ out2, float theta) {
  __shared__ float As[2][16][128];   // [buf][k][m]
  __shared__ float Bs[2][16][256];   // [buf][k][n] == contiguous copy of W rows
  const int bm = blockIdx.x * 128;
  const int tid = threadIdx.x;
  const int tx = tid & 15, ty = tid >> 4;
  const int wave = tid >> 6, lane = tid & 63;

  float acc[8][16];
#pragma unroll
  for (int i = 0; i < 8; ++i)
#pragma unroll
    for (int j = 0; j < 16; ++j) acc[i][j] = 0.f;

  // A staging geometry: thread owns row sm, k-range [sq, sq+8)
  const int sm = tid >> 1;            // 0..127
  const int sq = (tid & 1) * 8;       // 0 or 8
  const int gms = bm + sm;
  const bool mok = gms < N_NODES;
  const float* arow = A + (size_t)gms * K;

  const int nt = K / 16;

  // ---- prologue: stage tile 0 into buffer 0 ----
  {
#pragma unroll
    for (int j = 0; j < 4; ++j) {
      const int ch = j * 4 + wave;    // 0..15, 1KB chunks of the 16KB B tile
      async_copy16((char*)&Bs[0][0][0] + ch * 1024,
                   (const char*)W + (size_t)ch * 1024 + lane * 16);
    }
    float4 f0 = make_float4(0.f, 0.f, 0.f, 0.f), f1 = f0;
    if (mok) {
      f0 = *(const float4*)&arow[sq];
      f1 = *(const float4*)&arow[sq + 4];
    }
    As[0][sq + 0][sm] = f0.x; As[0][sq + 1][sm] = f0.y;
    As[0][sq + 2][sm] = f0.z; As[0][sq + 3][sm] = f0.w;
    As[0][sq + 4][sm] = f1.x; As[0][sq + 5][sm] = f1.y;
    As[0][sq + 6][sm] = f1.z; As[0][sq + 7][sm] = f1.w;
    __syncthreads();
  }

  int c = 0;
  for (int t = 0; t < nt; ++t) {
    float4 f0, f1;
    const bool pf = (t + 1 < nt);
    if (pf) {
      // issue next tile's loads BEFORE compute: B async -> LDS back buffer,
      // A -> registers (latency hides under the 2048-FMA compute phase)
      const size_t boff = (size_t)(t + 1) * 16384;
#pragma unroll
      for (int j = 0; j < 4; ++j) {
        const int ch = j * 4 + wave;
        async_copy16((char*)&Bs[c ^ 1][0][0] + ch * 1024,
                     (const char*)W + boff + (size_t)ch * 1024 + lane * 16);
      }
      f0 = make_float4(0.f, 0.f, 0.f, 0.f); f1 = f0;
      const int kn = (t + 1) * 16;
      if (mok) {
        f0 = *(const float4*)&arow[kn + sq];
        f1 = *(const float4*)&arow[kn + sq + 4];
      }
    }
    // compute current buffer
#pragma unroll
    for (int k = 0; k < 16; ++k) {
      float a[8], b[16];
      *(float4*)&a[0] = *(const float4*)&As[c][k][ty * 8];
      *(float4*)&a[4] = *(const float4*)&As[c][k][ty * 8 + 4];
      *(float4*)&b[0]  = *(const float4*)&Bs[c][k][tx * 4];
      *(float4*)&b[4]  = *(const float4*)&Bs[c][k][tx * 4 + 64];
      *(float4*)&b[8]  = *(const float4*)&Bs[c][k][tx * 4 + 128];
      *(float4*)&b[12] = *(const float4*)&Bs[c][k][tx * 4 + 192];
#pragma unroll
      for (int i = 0; i < 8; ++i)
#pragma unroll
        for (int j = 0; j < 16; ++j) acc[i][j] += a[i] * b[j];
    }
    if (pf) {
      // transpose A prefetch into back buffer (2-way bank alias = free)
      As[c ^ 1][sq + 0][sm] = f0.x; As[c ^ 1][sq + 1][sm] = f0.y;
      As[c ^ 1][sq + 2][sm] = f0.z; As[c ^ 1][sq + 3][sm] = f0.w;
      As[c ^ 1][sq + 4][sm] = f1.x; As[c ^ 1][sq + 5][sm] = f1.y;
      As[c ^ 1][sq + 6][sm] = f1.z; As[c ^ 1][sq + 7][sm] = f1.w;
    }
    __syncthreads();   // drains vmcnt (B async) + lgkmcnt (A writes)
    c ^= 1;
  }

  // epilogue: thread owns rows bm+ty*8..+7, cols tx*4 + {0,64,128,192}
  const int c0 = tx * 4;
  const float omt = 1.f - theta;
#pragma unroll
  for (int i = 0; i < 8; ++i) {
    int gm = bm + ty * 8 + i;
    if (gm >= N_NODES) continue;
    size_t base = (size_t)gm * NHID;
#pragma unroll
    for (int q = 0; q < 4; ++q) {
      size_t r = base + c0 + q * 64;
      if (MODE == 0) {
        float4 bb = *(const float4*)&bias[c0 + q * 64];
        float4 o;
        o.x = fmaxf(acc[i][q * 4 + 0] + bb.x, 0.f);
        o.y = fmaxf(acc[i][q * 4 + 1] + bb.y, 0.f);
        o.z = fmaxf(acc[i][q * 4 + 2] + bb.z, 0.f);
        o.w = fmaxf(acc[i][q * 4 + 3] + bb.w, 0.f);
        *(float4*)&out1[r] = o;
        *(float4*)&out2[r] = o;
      } else {
        float4 s = *(const float4*)&A[r];
        float4 hv = *(const float4*)&hin[r];
        float4 o;
        o.x = fmaxf(theta * acc[i][q * 4 + 0] + omt * s.x + hv.x, 0.f);
        o.y = fmaxf(theta * acc[i][q * 4 + 1] + omt * s.y + hv.y, 0.f);
        o.z = fmaxf(theta * acc[i][q * 4 + 2] + omt * s.z + hv.z, 0.f);
        o.w = fmaxf(theta * acc[i][q * 4 + 3] + omt * s.w + hv.w, 0.f);
        *(float4*)&out1[r] = o;
      }
    }
  }
}

// ---------------- head: out = sigmoid(h @ w1 + b1) ----------------
__global__ __launch_bounds__(256)
void k_final(const float* __restrict__ h, const float* __restrict__ w1,
             const float* __restrict__ b1, float* __restrict__ out) {
  __shared__ float ws[NHID * NCLASS];
  int t = threadIdx.x;
  for (int i = t; i < NHID * NCLASS; i += 256) ws[i] = w1[i];
  __syncthreads();
  int node = blockIdx.x * 16 + (t >> 4);
  int c = t & 15;
  if (node >= N_NODES) return;
  float acc = b1[c];
  const float* hr = &h[(size_t)node * NHID];
  for (int k = 0; k < NHID; k += 4) {
    float4 hv = *(const float4*)&hr[k];
    acc += hv.x * ws[(k + 0) * NCLASS + c];
    acc += hv.y * ws[(k + 1) * NCLASS + c];
    acc += hv.z * ws[(k + 2) * NCLASS + c];
    acc += hv.w * ws[(k + 3) * NCLASS + c];
  }
  out[(size_t)node * NCLASS + c] = 1.f / (1.f + __expf(-acc));
}

// ---------------- host ----------------
extern "C" void kernel_launch(void* const* d_in, const int* in_sizes, int n_in,
                              void* d_out, int out_size, void* d_ws, size_t ws_size,
                              hipStream_t stream) {
  const float* x        = (const float*)d_in[0];
  const int*   edge_src = (const int*)d_in[1];
  const int*   edge_dst = (const int*)d_in[2];
  const float* edge_w   = (const float*)d_in[3];
  const float* w0       = (const float*)d_in[4];
  const float* b0       = (const float*)d_in[5];
  const float* conv_w   = (const float*)d_in[6];
  const float* w1       = (const float*)d_in[7];
  const float* b1       = (const float*)d_in[8];
  float* out = (float*)d_out;

  char* ws = (char*)d_ws;
  size_t off = 0;
  auto alloc = [&](size_t bytes) {
    size_t o = off;
    off = (off + bytes + 255) & ~(size_t)255;
    return (void*)(ws + o);
  };
  float* h   = (float*)alloc((size_t)N_NODES * NHID * 4);
  float* h0  = (float*)alloc((size_t)N_NODES * NHID * 4);
  float* sup = (float*)alloc((size_t)N_NODES * NHID * 4);
  int*   rp  = (int*)alloc((size_t)(N_NODES + 1) * 4);
  int*   cnt = (int*)alloc((size_t)N_NODES * 4);
  int*   col = (int*)alloc((size_t)N_EDGES * 4);
  float* val = (float*)alloc((size_t)N_EDGES * 4);
  int*   bs  = (int*)alloc((size_t)NB * 4);
  (void)ws_size;

  // ---- CSR build ----
  hipMemsetAsync(cnt, 0, (size_t)N_NODES * 4, stream);
  k_hist<<<(N_EDGES + 255) / 256, 256, 0, stream>>>(edge_dst, cnt);
  k_blocksum<<<NB, 256, 0, stream>>>(cnt, bs);
  k_scan_top<<<1, 64, 0, stream>>>(bs, rp);
  k_scan_write<<<NB, 256, 0, stream>>>(cnt, bs, rp);
  hipMemsetAsync(cnt, 0, (size_t)N_NODES * 4, stream);
  k_fill<<<(N_EDGES + 255) / 256, 256, 0, stream>>>(edge_src, edge_dst, edge_w, rp,
                                                    cnt, col, val);

  // ---- h = relu(x@w0 + b0); h0 = h ----
  int gblocks = (N_NODES + 127) / 128;
  k_gemm<0><<<gblocks, 256, 0, stream>>>(x, w0, NFEAT, b0, nullptr, h, h0, 0.f);

  // ---- 8 GCNII layers ----
  for (int i = 0; i < NLAYERS; ++i) {
    float theta = logf(0.5f / (float)(i + 1) + 1.0f);
    k_spmm_half<<<(N_NODES + 3) / 4, 256, 0, stream>>>(rp, col, val, h, h0, sup, 0);
    k_spmm_half<<<(N_NODES + 3) / 4, 256, 0, stream>>>(rp, col, val, h, h0, sup, 128);
    const float* cw = conv_w + (size_t)i * NHID * NHID;
    k_gemm<1><<<gblocks, 256, 0, stream>>>(sup, cw, NHID, nullptr, h, h, nullptr, theta);
  }

  // ---- head ----
  k_final<<<(N_NODES + 15) / 16, 256, 0, stream>>>(h, w1, b1, out);
}

// Round 3
// 5855.458 us; speedup vs baseline: 3.8120x; 3.8120x over previous
//
#include <hip/hip_runtime.h>
#include <math.h>

#define N_NODES 100000
#define N_EDGES 3200000
#define NFEAT 512
#define NHID 256
#define NCLASS 16
#define NLAYERS 8

#define SCAN_CHUNK 1024
#define NB ((N_NODES + SCAN_CHUNK - 1) / SCAN_CHUNK)   // 98

typedef float f32x4 __attribute__((ext_vector_type(4)));
typedef short s16x8 __attribute__((ext_vector_type(8)));

__device__ __forceinline__ unsigned short bf16_rne(float f) {
  unsigned u = __float_as_uint(f);
  unsigned r = 0x7fffu + ((u >> 16) & 1u);
  return (unsigned short)((u + r) >> 16);
}
__device__ __forceinline__ float bf16_tof(unsigned short h) {
  return __uint_as_float(((unsigned)h) << 16);
}

// ---------------- CSR build ----------------
__global__ void k_hist(const int* __restrict__ dst, int* __restrict__ cnt) {
  int i = blockIdx.x * 256 + threadIdx.x;
  if (i < N_EDGES) atomicAdd(&cnt[dst[i]], 1);
}

__global__ void k_blocksum(const int* __restrict__ cnt, int* __restrict__ bs) {
  __shared__ int red[256];
  int b = blockIdx.x, t = threadIdx.x;
  int s = 0;
  int base = b * SCAN_CHUNK;
  for (int j = 0; j < 4; ++j) {
    int i = base + t + j * 256;
    if (i < N_NODES) s += cnt[i];
  }
  red[t] = s;
  __syncthreads();
  for (int off = 128; off > 0; off >>= 1) {
    if (t < off) red[t] += red[t + off];
    __syncthreads();
  }
  if (t == 0) bs[b] = red[0];
}

__global__ void k_scan_top(int* __restrict__ bs, int* __restrict__ rp) {
  if (threadIdx.x == 0) {
    int run = 0;
    for (int b = 0; b < NB; ++b) { int v = bs[b]; bs[b] = run; run += v; }
    rp[N_NODES] = run;
  }
}

__global__ void k_scan_write(const int* __restrict__ cnt, const int* __restrict__ bs,
                             int* __restrict__ rp) {
  __shared__ int tot[256];
  int b = blockIdx.x, t = threadIdx.x;
  int base = b * SCAN_CHUNK + t * 4;
  int v0 = 0, v1 = 0, v2 = 0, v3 = 0;
  if (base + 0 < N_NODES) v0 = cnt[base + 0];
  if (base + 1 < N_NODES) v1 = cnt[base + 1];
  if (base + 2 < N_NODES) v2 = cnt[base + 2];
  if (base + 3 < N_NODES) v3 = cnt[base + 3];
  int tsum = v0 + v1 + v2 + v3;
  tot[t] = tsum;
  __syncthreads();
  for (int off = 1; off < 256; off <<= 1) {
    int v = 0;
    if (t >= off) v = tot[t - off];
    __syncthreads();
    if (t >= off) tot[t] += v;
    __syncthreads();
  }
  int excl = tot[t] - tsum + bs[b];
  if (base + 0 < N_NODES) rp[base + 0] = excl;
  if (base + 1 < N_NODES) rp[base + 1] = excl + v0;
  if (base + 2 < N_NODES) rp[base + 2] = excl + v0 + v1;
  if (base + 3 < N_NODES) rp[base + 3] = excl + v0 + v1 + v2;
}

__global__ void k_fill(const int* __restrict__ src, const int* __restrict__ dst,
                       const float* __restrict__ w, const int* __restrict__ rp,
                       int* __restrict__ fill, int* __restrict__ col,
                       float* __restrict__ val) {
  int i = blockIdx.x * 256 + threadIdx.x;
  if (i < N_EDGES) {
    int d = dst[i];
    int pos = rp[d] + atomicAdd(&fill[d], 1);
    col[pos] = src[i];
    val[pos] = w[i];
  }
}

// ---------------- SpMM + fused support, feature-split (UNCHANGED, proven) ----
__global__ __launch_bounds__(256)
void k_spmm_half(const int* __restrict__ rp, const int* __restrict__ col,
                 const float* __restrict__ val, const float* __restrict__ h,
                 const float* __restrict__ h0, float* __restrict__ sup, int f0) {
  int wave = threadIdx.x >> 6;
  int lane = threadIdx.x & 63;
  int node = blockIdx.x * 4 + wave;
  if (node >= N_NODES) return;
  int e0 = rp[node], e1 = rp[node + 1];
  const float2* __restrict__ hv = (const float2*)h;  // row stride 128 float2
  int fo = (f0 >> 1) + lane;

  float2 a0 = make_float2(0.f, 0.f);
  float2 a1 = make_float2(0.f, 0.f);
  float2 a2 = make_float2(0.f, 0.f);
  float2 a3 = make_float2(0.f, 0.f);

  int e = e0;
  for (; e + 4 <= e1; e += 4) {
    int s0 = col[e], s1 = col[e + 1], s2 = col[e + 2], s3 = col[e + 3];
    float w0 = val[e], w1 = val[e + 1], w2 = val[e + 2], w3 = val[e + 3];
    float2 v0 = hv[(size_t)s0 * 128 + fo];
    float2 v1 = hv[(size_t)s1 * 128 + fo];
    float2 v2 = hv[(size_t)s2 * 128 + fo];
    float2 v3 = hv[(size_t)s3 * 128 + fo];
    a0.x += w0 * v0.x; a0.y += w0 * v0.y;
    a1.x += w1 * v1.x; a1.y += w1 * v1.y;
    a2.x += w2 * v2.x; a2.y += w2 * v2.y;
    a3.x += w3 * v3.x; a3.y += w3 * v3.y;
  }
  for (; e < e1; ++e) {
    int s0 = col[e];
    float w0 = val[e];
    float2 v0 = hv[(size_t)s0 * 128 + fo];
    a0.x += w0 * v0.x; a0.y += w0 * v0.y;
  }

  float2 acc;
  acc.x = (a0.x + a1.x) + (a2.x + a3.x);
  acc.y = (a0.y + a1.y) + (a2.y + a3.y);

  float2 z = ((const float2*)h0)[(size_t)node * 128 + fo];
  float2 o;
  o.x = 0.9f * acc.x + 0.1f * z.x;
  o.y = 0.9f * acc.y + 0.1f * z.y;
  ((float2*)sup)[(size_t)node * 128 + fo] = o;
}

// ---------------- W split: fp32 [K][256] -> bf16 hi/lo transposed [256][K] ---
__global__ void k_splitw(const float* __restrict__ W, unsigned short* __restrict__ hi,
                         unsigned short* __restrict__ lo, int K) {
  int mat = blockIdx.y;
  const float* Wm = W + (size_t)mat * K * NHID;
  unsigned short* hm = hi + (size_t)mat * K * NHID;
  unsigned short* lm = lo + (size_t)mat * K * NHID;
  int idx = blockIdx.x * 256 + threadIdx.x;
  if (idx >= K * NHID) return;
  int k = idx >> 8;          // NHID == 256
  int n = idx & 255;
  float f = Wm[idx];
  unsigned short h = bf16_rne(f);
  unsigned short l = bf16_rne(f - bf16_tof(h));
  hm[(size_t)n * K + k] = h;
  lm[(size_t)n * K + k] = l;
}

// ---------------- MFMA GEMM via bf16x3 split ----------------
// C = A@W with A fp32 split in-kernel to (hi, lo) bf16; W pre-split/transposed.
// C = Ahi*Whi + Ahi*Wlo + Alo*Whi  (dropped lo*lo term ~2^-16 relative).
// Tile 128x128, 4 waves, wave = 64x64 quadrant of 4x4 mfma_f32_16x16x32_bf16.
// Frag layouts (m89/m91-verified): A/B from [M][K]/[N][K] storage: lane&15 =
// row, k = (lane>>4)*8 + i; C/D: col = lane&15, row = (lane>>4)*4 + reg.
// LDS rows padded 32->40 bf16 (80 B): frag b128 reads hit each bank exactly
// 8x (the 1024B minimum) -> bank-balanced.
// MODE 0: out1 = out2 = relu(A@W + bias)                  (A = x,   K = 512)
// MODE 1: out1 = relu(theta*(A@W) + (1-theta)*A + hin)    (A = sup, K = 256)
#define PADK 40

template <int MODE>
__global__ __launch_bounds__(256)
void k_gemm_mfma(const float* __restrict__ A, const unsigned short* __restrict__ Bh_g,
                 const unsigned short* __restrict__ Bl_g, int K,
                 const float* __restrict__ bias, const float* __restrict__ hin,
                 float* __restrict__ out1, float* __restrict__ out2, float theta) {
  __shared__ unsigned short Ah[128][PADK];
  __shared__ unsigned short Al[128][PADK];
  __shared__ unsigned short Bh[128][PADK];
  __shared__ unsigned short Bl[128][PADK];
  const int bm = blockIdx.x * 128, bn = blockIdx.y * 128;
  const int tid = threadIdx.x;
  const int lane = tid & 63, wave = tid >> 6;
  const int wr = (wave >> 1) * 64;   // wave row quadrant
  const int wc = (wave & 1) * 64;    // wave col quadrant
  const int l16 = lane & 15, lk = lane >> 4;

  f32x4 acc[4][4];
#pragma unroll
  for (int i = 0; i < 4; ++i)
#pragma unroll
    for (int j = 0; j < 4; ++j)
#pragma unroll
      for (int q = 0; q < 4; ++q) acc[i][j][q] = 0.f;

  const int srow = tid >> 3;        // 0..31 (+32 per pass)
  const int skq = (tid & 7) * 4;    // k offset 0,4,..,28

  for (int kc = 0; kc < K; kc += 32) {
    // ---- stage A tile: fp32 -> hi/lo bf16 ----
#pragma unroll
    for (int it = 0; it < 4; ++it) {
      int row = srow + it * 32;
      int gm = bm + row;
      float4 f = make_float4(0.f, 0.f, 0.f, 0.f);
      if (gm < N_NODES) f = *(const float4*)&A[(size_t)gm * K + kc + skq];
      unsigned short h0 = bf16_rne(f.x), h1 = bf16_rne(f.y);
      unsigned short h2 = bf16_rne(f.z), h3 = bf16_rne(f.w);
      ushort4 hv = make_ushort4(h0, h1, h2, h3);
      ushort4 lv = make_ushort4(bf16_rne(f.x - bf16_tof(h0)),
                                bf16_rne(f.y - bf16_tof(h1)),
                                bf16_rne(f.z - bf16_tof(h2)),
                                bf16_rne(f.w - bf16_tof(h3)));
      *(ushort4*)&Ah[row][skq] = hv;
      *(ushort4*)&Al[row][skq] = lv;
    }
    // ---- stage B tiles (already bf16, [N][K] row-major) ----
#pragma unroll
    for (int it = 0; it < 4; ++it) {
      int row = srow + it * 32;
      size_t go = (size_t)(bn + row) * K + kc + skq;
      *(ushort4*)&Bh[row][skq] = *(const ushort4*)&Bh_g[go];
      *(ushort4*)&Bl[row][skq] = *(const ushort4*)&Bl_g[go];
    }
    __syncthreads();

    s16x8 ah[4], al[4], bh[4], bl[4];
#pragma unroll
    for (int i = 0; i < 4; ++i) {
      ah[i] = *(const s16x8*)&Ah[wr + i * 16 + l16][lk * 8];
      al[i] = *(const s16x8*)&Al[wr + i * 16 + l16][lk * 8];
      bh[i] = *(const s16x8*)&Bh[wc + i * 16 + l16][lk * 8];
      bl[i] = *(const s16x8*)&Bl[wc + i * 16 + l16][lk * 8];
    }
    // hi*hi sweep, then hi*lo, then lo*hi: each acc reused every 16 MFMAs
#pragma unroll
    for (int i = 0; i < 4; ++i)
#pragma unroll
      for (int j = 0; j < 4; ++j)
        acc[i][j] = __builtin_amdgcn_mfma_f32_16x16x32_bf16(ah[i], bh[j], acc[i][j], 0, 0, 0);
#pragma unroll
    for (int i = 0; i < 4; ++i)
#pragma unroll
      for (int j = 0; j < 4; ++j)
        acc[i][j] = __builtin_amdgcn_mfma_f32_16x16x32_bf16(ah[i], bl[j], acc[i][j], 0, 0, 0);
#pragma unroll
    for (int i = 0; i < 4; ++i)
#pragma unroll
      for (int j = 0; j < 4; ++j)
        acc[i][j] = __builtin_amdgcn_mfma_f32_16x16x32_bf16(al[i], bh[j], acc[i][j], 0, 0, 0);
    __syncthreads();
  }

  // ---- epilogue: C col = lane&15, row = lk*4 + q ----
  const float omt = 1.f - theta;
#pragma unroll
  for (int i = 0; i < 4; ++i) {
#pragma unroll
    for (int j = 0; j < 4; ++j) {
      int gn = bn + wc + j * 16 + l16;
#pragma unroll
      for (int q = 0; q < 4; ++q) {
        int gm = bm + wr + i * 16 + lk * 4 + q;
        if (gm >= N_NODES) continue;
        size_t r = (size_t)gm * NHID + gn;
        float v = acc[i][j][q];
        if (MODE == 0) {
          float o = fmaxf(v + bias[gn], 0.f);
          out1[r] = o;
          out2[r] = o;
        } else {
          float s = A[r];   // K == NHID for MODE 1, so stride matches
          float o = fmaxf(theta * v + omt * s + hin[r], 0.f);
          out1[r] = o;
        }
      }
    }
  }
}

// ---------------- head: out = sigmoid(h @ w1 + b1) ----------------
__global__ __launch_bounds__(256)
void k_final(const float* __restrict__ h, const float* __restrict__ w1,
             const float* __restrict__ b1, float* __restrict__ out) {
  __shared__ float ws[NHID * NCLASS];
  int t = threadIdx.x;
  for (int i = t; i < NHID * NCLASS; i += 256) ws[i] = w1[i];
  __syncthreads();
  int node = blockIdx.x * 16 + (t >> 4);
  int c = t & 15;
  if (node >= N_NODES) return;
  float acc = b1[c];
  const float* hr = &h[(size_t)node * NHID];
  for (int k = 0; k < NHID; k += 4) {
    float4 hv = *(const float4*)&hr[k];
    acc += hv.x * ws[(k + 0) * NCLASS + c];
    acc += hv.y * ws[(k + 1) * NCLASS + c];
    acc += hv.z * ws[(k + 2) * NCLASS + c];
    acc += hv.w * ws[(k + 3) * NCLASS + c];
  }
  out[(size_t)node * NCLASS + c] = 1.f / (1.f + __expf(-acc));
}

// ---------------- host ----------------
extern "C" void kernel_launch(void* const* d_in, const int* in_sizes, int n_in,
                              void* d_out, int out_size, void* d_ws, size_t ws_size,
                              hipStream_t stream) {
  const float* x        = (const float*)d_in[0];
  const int*   edge_src = (const int*)d_in[1];
  const int*   edge_dst = (const int*)d_in[2];
  const float* edge_w   = (const float*)d_in[3];
  const float* w0       = (const float*)d_in[4];
  const float* b0       = (const float*)d_in[5];
  const float* conv_w   = (const float*)d_in[6];
  const float* w1       = (const float*)d_in[7];
  const float* b1       = (const float*)d_in[8];
  float* out = (float*)d_out;

  char* ws = (char*)d_ws;
  size_t off = 0;
  auto alloc = [&](size_t bytes) {
    size_t o = off;
    off = (off + bytes + 255) & ~(size_t)255;
    return (void*)(ws + o);
  };
  float* h   = (float*)alloc((size_t)N_NODES * NHID * 4);
  float* h0  = (float*)alloc((size_t)N_NODES * NHID * 4);
  float* sup = (float*)alloc((size_t)N_NODES * NHID * 4);
  int*   rp  = (int*)alloc((size_t)(N_NODES + 1) * 4);
  int*   cnt = (int*)alloc((size_t)N_NODES * 4);
  int*   col = (int*)alloc((size_t)N_EDGES * 4);
  float* val = (float*)alloc((size_t)N_EDGES * 4);
  int*   bs  = (int*)alloc((size_t)NB * 4);
  unsigned short* w0t_hi = (unsigned short*)alloc((size_t)NFEAT * NHID * 2);
  unsigned short* w0t_lo = (unsigned short*)alloc((size_t)NFEAT * NHID * 2);
  unsigned short* cwt_hi = (unsigned short*)alloc((size_t)NLAYERS * NHID * NHID * 2);
  unsigned short* cwt_lo = (unsigned short*)alloc((size_t)NLAYERS * NHID * NHID * 2);
  (void)ws_size;

  // ---- CSR build ----
  (void)hipMemsetAsync(cnt, 0, (size_t)N_NODES * 4, stream);
  k_hist<<<(N_EDGES + 255) / 256, 256, 0, stream>>>(edge_dst, cnt);
  k_blocksum<<<NB, 256, 0, stream>>>(cnt, bs);
  k_scan_top<<<1, 64, 0, stream>>>(bs, rp);
  k_scan_write<<<NB, 256, 0, stream>>>(cnt, bs, rp);
  (void)hipMemsetAsync(cnt, 0, (size_t)N_NODES * 4, stream);
  k_fill<<<(N_EDGES + 255) / 256, 256, 0, stream>>>(edge_src, edge_dst, edge_w, rp,
                                                    cnt, col, val);

  // ---- split + transpose weights to bf16 hi/lo [N][K] ----
  k_splitw<<<dim3((NFEAT * NHID + 255) / 256, 1), 256, 0, stream>>>(w0, w0t_hi, w0t_lo, NFEAT);
  k_splitw<<<dim3((NHID * NHID + 255) / 256, NLAYERS), 256, 0, stream>>>(conv_w, cwt_hi, cwt_lo, NHID);

  // ---- h = relu(x@w0 + b0); h0 = h ----
  dim3 g0((N_NODES + 127) / 128, NHID / 128);
  k_gemm_mfma<0><<<g0, 256, 0, stream>>>(x, w0t_hi, w0t_lo, NFEAT, b0, nullptr, h, h0, 0.f);

  // ---- 8 GCNII layers ----
  for (int i = 0; i < NLAYERS; ++i) {
    float theta = logf(0.5f / (float)(i + 1) + 1.0f);
    k_spmm_half<<<(N_NODES + 3) / 4, 256, 0, stream>>>(rp, col, val, h, h0, sup, 0);
    k_spmm_half<<<(N_NODES + 3) / 4, 256, 0, stream>>>(rp, col, val, h, h0, sup, 128);
    const unsigned short* whi = cwt_hi + (size_t)i * NHID * NHID;
    const unsigned short* wlo = cwt_lo + (size_t)i * NHID * NHID;
    k_gemm_mfma<1><<<g0, 256, 0, stream>>>(sup, whi, wlo, NHID, nullptr, h, h, nullptr, theta);
  }

  // ---- head ----
  k_final<<<(N_NODES + 15) / 16, 256, 0, stream>>>(h, w1, b1, out);
}

// Round 4
// 5296.884 us; speedup vs baseline: 4.2140x; 1.1055x over previous
//
#include <hip/hip_runtime.h>
#include <math.h>

#define N_NODES 100000
#define N_EDGES 3200000
#define NFEAT 512
#define NHID 256
#define NCLASS 16
#define NLAYERS 8

#define SCAN_CHUNK 1024
#define NB ((N_NODES + SCAN_CHUNK - 1) / SCAN_CHUNK)   // 98

typedef float f32x4 __attribute__((ext_vector_type(4)));
typedef short s16x8 __attribute__((ext_vector_type(8)));

__device__ __forceinline__ unsigned short bf16_rne(float f) {
  unsigned u = __float_as_uint(f);
  unsigned r = 0x7fffu + ((u >> 16) & 1u);
  return (unsigned short)((u + r) >> 16);
}
__device__ __forceinline__ float bf16_tof(unsigned short h) {
  return __uint_as_float(((unsigned)h) << 16);
}

__device__ __forceinline__ void async16(void* lds_dst, const void* gsrc) {
  __builtin_amdgcn_global_load_lds(
      (const __attribute__((address_space(1))) unsigned int*)gsrc,
      (__attribute__((address_space(3))) unsigned int*)lds_dst, 16, 0, 0);
}

// ---------------- CSR build ----------------
__global__ void k_hist(const int* __restrict__ dst, int* __restrict__ cnt) {
  int i = blockIdx.x * 256 + threadIdx.x;
  if (i < N_EDGES) atomicAdd(&cnt[dst[i]], 1);
}

__global__ void k_blocksum(const int* __restrict__ cnt, int* __restrict__ bs) {
  __shared__ int red[256];
  int b = blockIdx.x, t = threadIdx.x;
  int s = 0;
  int base = b * SCAN_CHUNK;
  for (int j = 0; j < 4; ++j) {
    int i = base + t + j * 256;
    if (i < N_NODES) s += cnt[i];
  }
  red[t] = s;
  __syncthreads();
  for (int off = 128; off > 0; off >>= 1) {
    if (t < off) red[t] += red[t + off];
    __syncthreads();
  }
  if (t == 0) bs[b] = red[0];
}

__global__ void k_scan_top(int* __restrict__ bs, int* __restrict__ rp) {
  if (threadIdx.x == 0) {
    int run = 0;
    for (int b = 0; b < NB; ++b) { int v = bs[b]; bs[b] = run; run += v; }
    rp[N_NODES] = run;
  }
}

__global__ void k_scan_write(const int* __restrict__ cnt, const int* __restrict__ bs,
                             int* __restrict__ rp) {
  __shared__ int tot[256];
  int b = blockIdx.x, t = threadIdx.x;
  int base = b * SCAN_CHUNK + t * 4;
  int v0 = 0, v1 = 0, v2 = 0, v3 = 0;
  if (base + 0 < N_NODES) v0 = cnt[base + 0];
  if (base + 1 < N_NODES) v1 = cnt[base + 1];
  if (base + 2 < N_NODES) v2 = cnt[base + 2];
  if (base + 3 < N_NODES) v3 = cnt[base + 3];
  int tsum = v0 + v1 + v2 + v3;
  tot[t] = tsum;
  __syncthreads();
  for (int off = 1; off < 256; off <<= 1) {
    int v = 0;
    if (t >= off) v = tot[t - off];
    __syncthreads();
    if (t >= off) tot[t] += v;
    __syncthreads();
  }
  int excl = tot[t] - tsum + bs[b];
  if (base + 0 < N_NODES) rp[base + 0] = excl;
  if (base + 1 < N_NODES) rp[base + 1] = excl + v0;
  if (base + 2 < N_NODES) rp[base + 2] = excl + v0 + v1;
  if (base + 3 < N_NODES) rp[base + 3] = excl + v0 + v1 + v2;
}

__global__ void k_fill(const int* __restrict__ src, const int* __restrict__ dst,
                       const float* __restrict__ w, const int* __restrict__ rp,
                       int* __restrict__ fill, int* __restrict__ col,
                       float* __restrict__ val) {
  int i = blockIdx.x * 256 + threadIdx.x;
  if (i < N_EDGES) {
    int d = dst[i];
    int pos = rp[d] + atomicAdd(&fill[d], 1);
    col[pos] = src[i];
    val[pos] = w[i];
  }
}

// ---------------- SpMM + fused support, feature-split ----------------
// Proven-at-roofline gather structure; output changed to bf16 hi/lo pair
// (same total bytes as fp32 sup) so the GEMM can consume A without
// per-tile fp32->bf16 conversion and with global_load_lds staging.
__global__ __launch_bounds__(256)
void k_spmm_half(const int* __restrict__ rp, const int* __restrict__ col,
                 const float* __restrict__ val, const float* __restrict__ h,
                 const float* __restrict__ h0,
                 unsigned short* __restrict__ sup_hi,
                 unsigned short* __restrict__ sup_lo, int f0) {
  int wave = threadIdx.x >> 6;
  int lane = threadIdx.x & 63;
  int node = blockIdx.x * 4 + wave;
  if (node >= N_NODES) return;
  int e0 = rp[node], e1 = rp[node + 1];
  const float2* __restrict__ hv = (const float2*)h;  // row stride 128 float2
  int fo = (f0 >> 1) + lane;

  float2 a0 = make_float2(0.f, 0.f);
  float2 a1 = make_float2(0.f, 0.f);
  float2 a2 = make_float2(0.f, 0.f);
  float2 a3 = make_float2(0.f, 0.f);

  int e = e0;
  for (; e + 4 <= e1; e += 4) {
    int s0 = col[e], s1 = col[e + 1], s2 = col[e + 2], s3 = col[e + 3];
    float w0 = val[e], w1 = val[e + 1], w2 = val[e + 2], w3 = val[e + 3];
    float2 v0 = hv[(size_t)s0 * 128 + fo];
    float2 v1 = hv[(size_t)s1 * 128 + fo];
    float2 v2 = hv[(size_t)s2 * 128 + fo];
    float2 v3 = hv[(size_t)s3 * 128 + fo];
    a0.x += w0 * v0.x; a0.y += w0 * v0.y;
    a1.x += w1 * v1.x; a1.y += w1 * v1.y;
    a2.x += w2 * v2.x; a2.y += w2 * v2.y;
    a3.x += w3 * v3.x; a3.y += w3 * v3.y;
  }
  for (; e < e1; ++e) {
    int s0 = col[e];
    float w0 = val[e];
    float2 v0 = hv[(size_t)s0 * 128 + fo];
    a0.x += w0 * v0.x; a0.y += w0 * v0.y;
  }

  float2 acc;
  acc.x = (a0.x + a1.x) + (a2.x + a3.x);
  acc.y = (a0.y + a1.y) + (a2.y + a3.y);

  float2 z = ((const float2*)h0)[(size_t)node * 128 + fo];
  float ox = 0.9f * acc.x + 0.1f * z.x;
  float oy = 0.9f * acc.y + 0.1f * z.y;
  unsigned short hx = bf16_rne(ox), hy = bf16_rne(oy);
  unsigned short lx = bf16_rne(ox - bf16_tof(hx));
  unsigned short ly = bf16_rne(oy - bf16_tof(hy));
  ((ushort2*)sup_hi)[(size_t)node * 128 + fo] = make_ushort2(hx, hy);
  ((ushort2*)sup_lo)[(size_t)node * 128 + fo] = make_ushort2(lx, ly);
}

// ---------------- W split: fp32 [K][256] -> bf16 hi/lo transposed [256][K] ---
__global__ void k_splitw(const float* __restrict__ W, unsigned short* __restrict__ hi,
                         unsigned short* __restrict__ lo, int K) {
  int mat = blockIdx.y;
  const float* Wm = W + (size_t)mat * K * NHID;
  unsigned short* hm = hi + (size_t)mat * K * NHID;
  unsigned short* lm = lo + (size_t)mat * K * NHID;
  int idx = blockIdx.x * 256 + threadIdx.x;
  if (idx >= K * NHID) return;
  int k = idx >> 8;          // NHID == 256
  int n = idx & 255;
  float f = Wm[idx];
  unsigned short h = bf16_rne(f);
  unsigned short l = bf16_rne(f - bf16_tof(h));
  hm[(size_t)n * K + k] = h;
  lm[(size_t)n * K + k] = l;
}

// ---------------- MFMA GEMM, 128x256 tile, BK=32, double-buffered -----------
// 8 waves (2 row x 4 col quadrants of 64x64), mfma_f32_16x16x32_bf16,
// C = Ahi*Bhi + Ahi*Blo + Alo*Bhi (lo*lo dropped, ~1.5e-5 rel).
//
// LDS is FRAGMENT-ORDERED: slot L = fragblock*64 + (row&15) + (k>>3)*16,
// 16 B per slot. Frag read addr = base + lane*16 -> perfectly linear per
// wave = ZERO bank conflicts by construction (fixes round-3's 12.8M).
// This order also matches global_load_lds's wave-uniform-base + lane*16
// write pattern exactly, so A (MODE 1) and B stage via async DMA, double
// buffered: t+1's 6 gload_lds fly during t's 48 MFMAs; 1 barrier/K-step.
// MODE 0 converts fp32 x in-kernel (runs once): loads issued before MFMA,
// convert+ds_write after (T14 split).
//
// Epilogue: acc -> LDS (fp32, rows padded to 260 floats to avoid lk-bank
// aliasing) -> coalesced float4 global IO in 4 row-chunks of 32.
// MODE 0: out1 = out2 = relu(A@W + bias)                  (A = x,   K = 512)
// MODE 1: out1 = relu(theta*(A@W) + (1-theta)*s + hin), s = hi+lo (K = 256)
//
// Short-offsets in pool: AH: 0 + buf*4096 | AL: 8192 + buf*4096
//                        BH: 16384 + buf*8192 | BL: 32768 + buf*8192  (96 KB)
template <int MODE>
__global__ __launch_bounds__(512)
void k_gemm2(const float* __restrict__ Af,
             const unsigned short* __restrict__ Ah_g,
             const unsigned short* __restrict__ Al_g,
             const unsigned short* __restrict__ Bh_g,
             const unsigned short* __restrict__ Bl_g, int K,
             const float* __restrict__ bias, const float* __restrict__ hin,
             float* __restrict__ out1, float* __restrict__ out2, float theta) {
  __shared__ unsigned short pool[49152];   // 96 KB
  const int tid = threadIdx.x;
  const int lane = tid & 63, w = tid >> 6;
  const int wr = w >> 2, wc = w & 3;
  const int l16 = lane & 15, lk = lane >> 4;
  const int bm = blockIdx.x * 128;

  f32x4 acc[4][4];
#pragma unroll
  for (int i = 0; i < 4; ++i)
#pragma unroll
    for (int j = 0; j < 4; ++j)
#pragma unroll
      for (int q = 0; q < 4; ++q) acc[i][j][q] = 0.f;

  // ---- staging helpers ----
  // B: 16 frag-blocks/array; wave stages blocks w*2, w*2+1 of hi and lo.
  auto stageB = [&](int buf, int kc) {
#pragma unroll
    for (int u = 0; u < 2; ++u) {
      int fb = w * 2 + u;
      size_t go = (size_t)(fb * 16 + l16) * K + kc + lk * 8;
      async16(&pool[16384 + buf * 8192 + fb * 512], &Bh_g[go]);
      async16(&pool[32768 + buf * 8192 + fb * 512], &Bl_g[go]);
    }
  };
  // A (MODE 1, bf16): 8 frag-blocks/array; wave stages block w of hi and lo.
  auto stageA1 = [&](int buf, int kc) {
    size_t go = (size_t)(bm + w * 16 + l16) * K + kc + lk * 8;
    async16(&pool[0 + buf * 4096 + w * 512], &Ah_g[go]);
    async16(&pool[8192 + buf * 4096 + w * 512], &Al_g[go]);
  };
  // A (MODE 0, fp32 -> split in-kernel): 2 float4 per thread
  float4 fa0, fa1;
  auto stageA0_issue = [&](int kc) {
    int m0 = tid >> 3, k00 = (tid & 7) * 4;           // task tid
    int m1 = (tid + 512) >> 3, k01 = ((tid + 512) & 7) * 4;
    fa0 = make_float4(0.f, 0.f, 0.f, 0.f);
    fa1 = fa0;
    if (bm + m0 < N_NODES) fa0 = *(const float4*)&Af[(size_t)(bm + m0) * K + kc + k00];
    if (bm + m1 < N_NODES) fa1 = *(const float4*)&Af[(size_t)(bm + m1) * K + kc + k01];
  };
  auto stageA0_write = [&](int buf) {
#pragma unroll
    for (int p = 0; p < 2; ++p) {
      int f = tid + p * 512;
      int m = f >> 3, k0 = (f & 7) * 4;
      float4 fv = p ? fa1 : fa0;
      int L = (m >> 4) * 64 + (m & 15) + (k0 >> 3) * 16;
      unsigned short h0 = bf16_rne(fv.x), h1 = bf16_rne(fv.y);
      unsigned short h2 = bf16_rne(fv.z), h3 = bf16_rne(fv.w);
      ushort4 hv = make_ushort4(h0, h1, h2, h3);
      ushort4 lv = make_ushort4(bf16_rne(fv.x - bf16_tof(h0)),
                                bf16_rne(fv.y - bf16_tof(h1)),
                                bf16_rne(fv.z - bf16_tof(h2)),
                                bf16_rne(fv.w - bf16_tof(h3)));
      *(ushort4*)&pool[0 + buf * 4096 + L * 8 + (k0 & 7)] = hv;
      *(ushort4*)&pool[8192 + buf * 4096 + L * 8 + (k0 & 7)] = lv;
    }
  };

  // ---- prologue: stage tile 0 into buf 0 ----
  if (MODE == 0) { stageA0_issue(0); stageA0_write(0); }
  else stageA1(0, 0);
  stageB(0, 0);
  __syncthreads();

  const int nt = K / 32;
  int buf = 0;
  for (int t = 0; t < nt; ++t) {
    const bool pf = (t + 1 < nt);
    if (pf) {   // issue t+1 loads before compute; latency hides under MFMAs
      if (MODE == 0) stageA0_issue((t + 1) * 32);
      else stageA1(buf ^ 1, (t + 1) * 32);
      stageB(buf ^ 1, (t + 1) * 32);
    }
    // frag reads: base + lane*16B, linear -> conflict-free
    s16x8 ah[4], al[4], bh[4], bl[4];
#pragma unroll
    for (int i = 0; i < 4; ++i) {
      int fb = wr * 4 + i;
      ah[i] = *(const s16x8*)&pool[0 + buf * 4096 + fb * 512 + lane * 8];
      al[i] = *(const s16x8*)&pool[8192 + buf * 4096 + fb * 512 + lane * 8];
    }
#pragma unroll
    for (int j = 0; j < 4; ++j) {
      int fb = wc * 4 + j;
      bh[j] = *(const s16x8*)&pool[16384 + buf * 8192 + fb * 512 + lane * 8];
      bl[j] = *(const s16x8*)&pool[32768 + buf * 8192 + fb * 512 + lane * 8];
    }
#pragma unroll
    for (int i = 0; i < 4; ++i)
#pragma unroll
      for (int j = 0; j < 4; ++j)
        acc[i][j] = __builtin_amdgcn_mfma_f32_16x16x32_bf16(ah[i], bh[j], acc[i][j], 0, 0, 0);
#pragma unroll
    for (int i = 0; i < 4; ++i)
#pragma unroll
      for (int j = 0; j < 4; ++j)
        acc[i][j] = __builtin_amdgcn_mfma_f32_16x16x32_bf16(ah[i], bl[j], acc[i][j], 0, 0, 0);
#pragma unroll
    for (int i = 0; i < 4; ++i)
#pragma unroll
      for (int j = 0; j < 4; ++j)
        acc[i][j] = __builtin_amdgcn_mfma_f32_16x16x32_bf16(al[i], bh[j], acc[i][j], 0, 0, 0);
    if (MODE == 0 && pf) stageA0_write(buf ^ 1);  // after MFMAs (T14)
    __syncthreads();
    buf ^= 1;
  }

  // ---- epilogue: LDS transpose in 4 chunks of 32 rows ----
  float* Cst = (float*)pool;              // [32][260] fp32 = 33280 B
  const float omt = 1.f - theta;
  for (int g = 0; g < 4; ++g) {
    if (wr == (g >> 1)) {
#pragma unroll
      for (int ii = 0; ii < 2; ++ii) {
        int i = (g & 1) * 2 + ii;
#pragma unroll
        for (int j = 0; j < 4; ++j) {
          int colc = wc * 64 + j * 16 + l16;
#pragma unroll
          for (int q = 0; q < 4; ++q) {
            int lr = ii * 16 + lk * 4 + q;
            Cst[lr * 260 + colc] = acc[i][j][q];
          }
        }
      }
    }
    __syncthreads();
#pragma unroll
    for (int p = 0; p < 4; ++p) {
      int f = tid + p * 512;              // 0..2047
      int row = f >> 6, c4 = (f & 63) * 4;
      int gm = bm + g * 32 + row;
      if (gm < N_NODES) {
        float4 v = *(const float4*)&Cst[row * 260 + c4];
        size_t r = (size_t)gm * NHID + c4;
        float4 o;
        if (MODE == 0) {
          float4 bb = *(const float4*)&bias[c4];
          o.x = fmaxf(v.x + bb.x, 0.f);
          o.y = fmaxf(v.y + bb.y, 0.f);
          o.z = fmaxf(v.z + bb.z, 0.f);
          o.w = fmaxf(v.w + bb.w, 0.f);
          *(float4*)&out1[r] = o;
          *(float4*)&out2[r] = o;
        } else {
          ushort4 sh = *(const ushort4*)&Ah_g[r];   // K == NHID in MODE 1
          ushort4 sl = *(const ushort4*)&Al_g[r];
          float4 hv = *(const float4*)&hin[r];
          float sx = bf16_tof(sh.x) + bf16_tof(sl.x);
          float sy = bf16_tof(sh.y) + bf16_tof(sl.y);
          float sz = bf16_tof(sh.z) + bf16_tof(sl.z);
          float sw = bf16_tof(sh.w) + bf16_tof(sl.w);
          o.x = fmaxf(theta * v.x + omt * sx + hv.x, 0.f);
          o.y = fmaxf(theta * v.y + omt * sy + hv.y, 0.f);
          o.z = fmaxf(theta * v.z + omt * sz + hv.z, 0.f);
          o.w = fmaxf(theta * v.w + omt * sw + hv.w, 0.f);
          *(float4*)&out1[r] = o;
        }
      }
    }
    __syncthreads();
  }
}

// ---------------- head: out = sigmoid(h @ w1 + b1) ----------------
__global__ __launch_bounds__(256)
void k_final(const float* __restrict__ h, const float* __restrict__ w1,
             const float* __restrict__ b1, float* __restrict__ out) {
  __shared__ float ws[NHID * NCLASS];
  int t = threadIdx.x;
  for (int i = t; i < NHID * NCLASS; i += 256) ws[i] = w1[i];
  __syncthreads();
  int node = blockIdx.x * 16 + (t >> 4);
  int c = t & 15;
  if (node >= N_NODES) return;
  float acc = b1[c];
  const float* hr = &h[(size_t)node * NHID];
  for (int k = 0; k < NHID; k += 4) {
    float4 hv = *(const float4*)&hr[k];
    acc += hv.x * ws[(k + 0) * NCLASS + c];
    acc += hv.y * ws[(k + 1) * NCLASS + c];
    acc += hv.z * ws[(k + 2) * NCLASS + c];
    acc += hv.w * ws[(k + 3) * NCLASS + c];
  }
  out[(size_t)node * NCLASS + c] = 1.f / (1.f + __expf(-acc));
}

// ---------------- host ----------------
extern "C" void kernel_launch(void* const* d_in, const int* in_sizes, int n_in,
                              void* d_out, int out_size, void* d_ws, size_t ws_size,
                              hipStream_t stream) {
  const float* x        = (const float*)d_in[0];
  const int*   edge_src = (const int*)d_in[1];
  const int*   edge_dst = (const int*)d_in[2];
  const float* edge_w   = (const float*)d_in[3];
  const float* w0       = (const float*)d_in[4];
  const float* b0       = (const float*)d_in[5];
  const float* conv_w   = (const float*)d_in[6];
  const float* w1       = (const float*)d_in[7];
  const float* b1       = (const float*)d_in[8];
  float* out = (float*)d_out;

  char* ws = (char*)d_ws;
  size_t off = 0;
  auto alloc = [&](size_t bytes) {
    size_t o = off;
    off = (off + bytes + 255) & ~(size_t)255;
    return (void*)(ws + o);
  };
  float* h    = (float*)alloc((size_t)N_NODES * NHID * 4);
  float* h0   = (float*)alloc((size_t)N_NODES * NHID * 4);
  unsigned short* sup_hi = (unsigned short*)alloc((size_t)N_NODES * NHID * 2);
  unsigned short* sup_lo = (unsigned short*)alloc((size_t)N_NODES * NHID * 2);
  int*   col = (int*)alloc((size_t)N_EDGES * 4);      // after sup_lo: OOB-safe pad
  float* val = (float*)alloc((size_t)N_EDGES * 4);
  int*   rp  = (int*)alloc((size_t)(N_NODES + 1) * 4);
  int*   cnt = (int*)alloc((size_t)N_NODES * 4);
  int*   bs  = (int*)alloc((size_t)NB * 4);
  unsigned short* w0t_hi = (unsigned short*)alloc((size_t)NFEAT * NHID * 2);
  unsigned short* w0t_lo = (unsigned short*)alloc((size_t)NFEAT * NHID * 2);
  unsigned short* cwt_hi = (unsigned short*)alloc((size_t)NLAYERS * NHID * NHID * 2);
  unsigned short* cwt_lo = (unsigned short*)alloc((size_t)NLAYERS * NHID * NHID * 2);
  (void)ws_size;

  // ---- CSR build ----
  (void)hipMemsetAsync(cnt, 0, (size_t)N_NODES * 4, stream);
  k_hist<<<(N_EDGES + 255) / 256, 256, 0, stream>>>(edge_dst, cnt);
  k_blocksum<<<NB, 256, 0, stream>>>(cnt, bs);
  k_scan_top<<<1, 64, 0, stream>>>(bs, rp);
  k_scan_write<<<NB, 256, 0, stream>>>(cnt, bs, rp);
  (void)hipMemsetAsync(cnt, 0, (size_t)N_NODES * 4, stream);
  k_fill<<<(N_EDGES + 255) / 256, 256, 0, stream>>>(edge_src, edge_dst, edge_w, rp,
                                                    cnt, col, val);

  // ---- split + transpose weights to bf16 hi/lo [N][K] ----
  k_splitw<<<dim3((NFEAT * NHID + 255) / 256, 1), 256, 0, stream>>>(w0, w0t_hi, w0t_lo, NFEAT);
  k_splitw<<<dim3((NHID * NHID + 255) / 256, NLAYERS), 256, 0, stream>>>(conv_w, cwt_hi, cwt_lo, NHID);

  // ---- h = relu(x@w0 + b0); h0 = h ----
  int gblocks = (N_NODES + 127) / 128;   // 782
  k_gemm2<0><<<gblocks, 512, 0, stream>>>(x, nullptr, nullptr, w0t_hi, w0t_lo,
                                          NFEAT, b0, nullptr, h, h0, 0.f);

  // ---- 8 GCNII layers ----
  for (int i = 0; i < NLAYERS; ++i) {
    float theta = logf(0.5f / (float)(i + 1) + 1.0f);
    k_spmm_half<<<(N_NODES + 3) / 4, 256, 0, stream>>>(rp, col, val, h, h0,
                                                       sup_hi, sup_lo, 0);
    k_spmm_half<<<(N_NODES + 3) / 4, 256, 0, stream>>>(rp, col, val, h, h0,
                                                       sup_hi, sup_lo, 128);
    const unsigned short* whi = cwt_hi + (size_t)i * NHID * NHID;
    const unsigned short* wlo = cwt_lo + (size_t)i * NHID * NHID;
    k_gemm2<1><<<gblocks, 512, 0, stream>>>(nullptr, sup_hi, sup_lo, whi, wlo,
                                            NHID, nullptr, h, h, nullptr, theta);
  }

  // ---- head ----
  k_final<<<(N_NODES + 15) / 16, 256, 0, stream>>>(h, w1, b1, out);
}